// Round 6
// baseline (2806.862 us; speedup 1.0000x reference)
//
#include <hip/hip_runtime.h>
#include <hip/hip_bf16.h>
#include <math.h>

#define BB 32
#define SS 256
#define EE 768
#define HH 512
#define GG 2048   // 4*H
#define NCLS 30
#define NWG 16    // workgroups per LSTM direction

typedef __attribute__((ext_vector_type(8))) short bf16x8;
typedef __attribute__((ext_vector_type(4))) float f32x4;
typedef unsigned long long u64;

__device__ inline unsigned short f2bf(float f) {
  union { float f; unsigned int u; } v; v.f = f;
  unsigned int r = v.u + 0x7fffu + ((v.u >> 16) & 1u);
  return (unsigned short)(r >> 16);
}
__device__ inline float bf2f(unsigned short u) {
  union { unsigned int u; float f; } v; v.u = ((unsigned int)u) << 16;
  return v.f;
}
__device__ inline float sigm(float x) { return 1.f / (1.f + expf(-x)); }

__device__ inline void load_lds16(const void* g, void* l) {
  __builtin_amdgcn_global_load_lds(
      (const __attribute__((address_space(1))) void*)g,
      (__attribute__((address_space(3))) void*)l, 16, 0, 0);
}

// agent-scope coherent ops (visible at the MALL; 8B aligned = single-copy atomic)
__device__ inline u64 aload64(const u64* p) {
  return __hip_atomic_load(p, __ATOMIC_RELAXED, __HIP_MEMORY_SCOPE_AGENT);
}
__device__ inline void astore64(u64* p, u64 v) {
  __hip_atomic_store(p, v, __ATOMIC_RELAXED, __HIP_MEMORY_SCOPE_AGENT);
}

// ---------------- weight conversion (fp32 -> bf16, with K padding) ----------
__global__ void k_convpad(const float* __restrict__ src, unsigned short* __restrict__ dst,
                          int R, int Ks, int Kd) {
  int n = R * Kd;
  for (int i = blockIdx.x * blockDim.x + threadIdx.x; i < n; i += gridDim.x * blockDim.x) {
    int r = i / Kd, k = i - r * Kd;
    dst[i] = (k < Ks) ? f2bf(src[(size_t)r * Ks + k]) : (unsigned short)0;
  }
}

__global__ void k_biassum(const float* __restrict__ a, const float* __restrict__ b,
                          float* __restrict__ o) {
  int i = blockIdx.x * 256 + threadIdx.x;
  if (i < GG) o[i] = a[i] + b[i];
}

// ---------------- h-exchange buffer init: slot0 LSB=0, slot1 LSB=1 ---------
// (so re-poisoned 0xAA or stale data can never alias as a valid tag)
__global__ void k_hinit(u64* __restrict__ h0, u64* __restrict__ h1) {
  int i = blockIdx.x * 256 + threadIdx.x;  // [dir][slot][4096] = 16384 per layer
  if (i < 16384) {
    u64 v = ((i >> 12) & 1) ? 0x0001000100010001ULL : 0ULL;
    h0[i] = v;
    h1[i] = v;
  }
}

// ---------------- idx_pred[b] = argmax (first max) of predicates -----------
__global__ void k_idxpred(const int* __restrict__ pred, int* __restrict__ idxp) {
  int b = blockIdx.x, l = threadIdx.x;  // 64 threads
  const int* pb = pred + b * SS;
  int4 v = *(const int4*)(pb + l * 4);
  int loc = 0x7fffffff;
  if (v.w == 1) loc = 4 * l + 3;
  if (v.z == 1) loc = 4 * l + 2;
  if (v.y == 1) loc = 4 * l + 1;
  if (v.x == 1) loc = 4 * l + 0;
  for (int off = 32; off > 0; off >>= 1) {
    int o = __shfl_down(loc, off);
    loc = min(loc, o);
  }
  if (l == 0) idxp[b] = (loc == 0x7fffffff) ? 0 : loc;
}

// ---------------- A0 build + fused mean_word (single pass over hs) ---------
__global__ void k_buildA0(const float* __restrict__ hs, const int* __restrict__ roles,
                          float* __restrict__ mw, unsigned short* __restrict__ A0) {
  int blk = blockIdx.x;           // s*32 + b
  int s = blk >> 5, b = blk & 31;
  unsigned short* row = A0 + (size_t)blk * 800;
  size_t base = ((size_t)b * SS + s) * EE;
  const size_t LSTR = (size_t)BB * SS * EE;
  __shared__ float red[256];
  float part = 0.f;
  for (int k = threadIdx.x; k < EE; k += 256) {
    float v = (hs[base + k] + hs[base + LSTR + k] + hs[base + 2 * LSTR + k] +
               hs[base + 3 * LSTR + k]) * 0.25f;
    part += v;
    row[k] = f2bf(v);
  }
  red[threadIdx.x] = part;
  __syncthreads();
  for (int s2 = 128; s2 > 0; s2 >>= 1) {
    if (threadIdx.x < s2) red[threadIdx.x] += red[threadIdx.x + s2];
    __syncthreads();
  }
  if (threadIdx.x == 0) mw[b * SS + s] = red[0] * (1.f / 768.f);
  if (threadIdx.x == 1) {
    int rl = roles[b * SS + s];
    row[769] = f2bf((rl != 0 && rl != -100) ? 1.f : 0.f);
  }
  if (threadIdx.x < 30) row[770 + threadIdx.x] = 0;
}

// fill the predicate-relative delta feature (col 768) after idxp is known
__global__ void k_predfeat(const float* __restrict__ mw, const int* __restrict__ idxp,
                           unsigned short* __restrict__ A0) {
  int i = blockIdx.x * 256 + threadIdx.x;  // b*256 + s
  int b = i >> 8, s = i & 255;
  float d = mw[i] - mw[b * SS + idxp[b]];
  A0[(size_t)(s * 32 + b) * 800 + 768] = f2bf(d);
}

// ---------------- GEMM-BT: C[s][n][b] = A[s*32+b][:] . W[n][:] + bias[n] ---
// A: [8192, K] bf16 ; W: [2048, K] bf16 ; C: fp32 [256][2048][32]
__global__ __launch_bounds__(256) void k_gemm_bt(const unsigned short* __restrict__ A,
                                                 const unsigned short* __restrict__ W,
                                                 const float* __restrict__ bias,
                                                 float* __restrict__ C, int K) {
  __shared__ unsigned short As[128 * 32];
  __shared__ unsigned short Bs[128 * 32];
  const int tid = threadIdx.x;
  const int wave = tid >> 6, lane = tid & 63;
  const int l15 = lane & 15, quad = lane >> 4;
  const int m0 = blockIdx.y * 128, n0 = blockIdx.x * 128;
  const int wr = (wave >> 1) * 64, wc = (wave & 1) * 64;
  const int srow = wave * 16 + (lane >> 2);
  const int scol = (lane & 3) * 8;

  f32x4 acc[4][4];
#pragma unroll
  for (int i = 0; i < 4; i++)
#pragma unroll
    for (int j = 0; j < 4; j++) acc[i][j] = (f32x4){0.f, 0.f, 0.f, 0.f};

  for (int k0 = 0; k0 < K; k0 += 32) {
#pragma unroll
    for (int rep = 0; rep < 2; rep++) {
      load_lds16(A + (size_t)(m0 + rep * 64 + srow) * K + k0 + scol,
                 &As[(rep * 64 + wave * 16) * 32]);
      load_lds16(W + (size_t)(n0 + rep * 64 + srow) * K + k0 + scol,
                 &Bs[(rep * 64 + wave * 16) * 32]);
    }
    __syncthreads();
    bf16x8 af[4], bfr[4];
#pragma unroll
    for (int i = 0; i < 4; i++) af[i] = *(const bf16x8*)&As[(wr + i * 16 + l15) * 32 + quad * 8];
#pragma unroll
    for (int j = 0; j < 4; j++) bfr[j] = *(const bf16x8*)&Bs[(wc + j * 16 + l15) * 32 + quad * 8];
#pragma unroll
    for (int i = 0; i < 4; i++)
#pragma unroll
      for (int j = 0; j < 4; j++)
        acc[i][j] = __builtin_amdgcn_mfma_f32_16x16x32_bf16(af[i], bfr[j], acc[i][j], 0, 0, 0);
    __syncthreads();
  }

#pragma unroll
  for (int j = 0; j < 4; j++) {
    int n = n0 + wc + j * 16 + l15;
    float bv = bias[n];
#pragma unroll
    for (int i = 0; i < 4; i++) {
      int m = m0 + wr + i * 16 + quad * 4;  // row = s*32+b, 4 consecutive b
      int s = m >> 5, b = m & 31;
      f32x4 v = acc[i][j];
      f32x4 outv = {v[0] + bv, v[1] + bv, v[2] + bv, v[3] + bv};
      *(f32x4*)(C + ((size_t)s * GG + n) * BB + b) = outv;
    }
  }
}

// ---------------- persistent BiLSTM recurrence (one layer) ------------------
// 32 WGs: dir = wg>>4, slice = wg&15 -> hidden units [32*slice, +32)
// wave w = gate type w (i,f,g,o), rows w*512 + u0 + [0,32)
// Cross-WG h exchange: SELF-VALIDATING h. Each bf16 h value's mantissa LSB is
// forced to a 1-bit epoch tag T=((t+1)>>1)&1; with the parity double-buffer
// slot this uniquely distinguishes the two writes that share a slot. Producers
// fire-and-forget one relaxed agent-scope 8B store (no drain, no flag);
// consumers stage h with 16 pipelined coherent loads, retrying only stale
// granules in parallel batches (R4's waterfall + tag-volume mistakes avoided).
// R5 chain cost removed: vmcnt drain (~700cy) + flag store (~700cy) + poll
// detect (~500cy) per step.
__global__ __launch_bounds__(256, 1) void k_recurrent(const float* __restrict__ xWf,
                                                      const float* __restrict__ xWb,
                                                      const unsigned short* __restrict__ WhhF,
                                                      const unsigned short* __restrict__ WhhB,
                                                      u64* __restrict__ hbuf,
                                                      unsigned short* __restrict__ Hout) {
  const int wg = blockIdx.x, dir = wg >> 4, slice = wg & 15;
  const int tid = threadIdx.x, wave = tid >> 6, lane = tid & 63;
  const int l15 = lane & 15, quad = lane >> 4;
  const int u0 = slice * 32;
  const unsigned short* Whh = dir ? WhhB : WhhF;
  const float* xW = dir ? xWb : xWf;
  u64* hbT = hbuf + (size_t)dir * 8192;     // 2 slots x 4096 granules (8B = 4 units)

  // h staging in LDS: [batch 32][528 shorts] (+16 pad -> max 4-way aliasing)
  __shared__ __attribute__((aligned(16))) short hlds[32][528];
  __shared__ float gbuf[4][32][32];  // [gate][batch][unit_local]

  // zero h(t=0)
  for (int i = tid; i < 32 * 264; i += 256) ((unsigned int*)hlds)[i] = 0;

  // Whh B-fragments resident in registers: 2 n-tiles x 16 k-steps = 128 VGPRs
  bf16x8 bfrag[2][16];
#pragma unroll
  for (int j = 0; j < 2; j++) {
    const unsigned short* wrow = Whh + (size_t)(wave * HH + u0 + j * 16 + l15) * HH + quad * 8;
#pragma unroll
    for (int kk = 0; kk < 16; kk++) bfrag[j][kk] = *(const bf16x8*)(wrow + kk * 32);
  }

  const int cb = tid >> 3;           // batch this thread updates (32)
  const int cu = (tid & 7) * 4;      // 4 consecutive local units
  float cst[4] = {0.f, 0.f, 0.f, 0.f};

  // stager identity: thread stages granule column guc (= unit/4) across batches
  const int guc = tid & 127;
  const int bb0 = tid >> 7;          // 0 or 1
  const bool ownCol = ((guc >> 3) == slice);

  // prefetch xW for t=0
  f32x4 xv[2][2];
  {
    const int time0 = dir ? (SS - 1) : 0;
#pragma unroll
    for (int j = 0; j < 2; j++)
#pragma unroll
      for (int i = 0; i < 2; i++)
        xv[i][j] = *(const f32x4*)(xW + ((size_t)time0 * GG + wave * HH + u0 + j * 16 + l15) * BB +
                                   i * 16 + quad * 4);
  }
  __syncthreads();

  for (int t = 0; t < SS; t++) {
    const int time = dir ? (SS - 1 - t) : t;

    f32x4 acc[2][2];
#pragma unroll
    for (int i = 0; i < 2; i++)
#pragma unroll
      for (int j = 0; j < 2; j++) acc[i][j] = xv[i][j];

#pragma unroll
    for (int kk = 0; kk < 16; kk++) {
      bf16x8 a0 = *(const bf16x8*)&hlds[l15][quad * 8 + kk * 32];
      bf16x8 a1 = *(const bf16x8*)&hlds[16 + l15][quad * 8 + kk * 32];
      acc[0][0] = __builtin_amdgcn_mfma_f32_16x16x32_bf16(a0, bfrag[0][kk], acc[0][0], 0, 0, 0);
      acc[0][1] = __builtin_amdgcn_mfma_f32_16x16x32_bf16(a0, bfrag[1][kk], acc[0][1], 0, 0, 0);
      acc[1][0] = __builtin_amdgcn_mfma_f32_16x16x32_bf16(a1, bfrag[0][kk], acc[1][0], 0, 0, 0);
      acc[1][1] = __builtin_amdgcn_mfma_f32_16x16x32_bf16(a1, bfrag[1][kk], acc[1][1], 0, 0, 0);
    }
#pragma unroll
    for (int i = 0; i < 2; i++)
#pragma unroll
      for (int j = 0; j < 2; j++)
#pragma unroll
        for (int r = 0; r < 4; r++)
          gbuf[wave][i * 16 + quad * 4 + r][j * 16 + l15] = acc[i][j][r];
    __syncthreads();   // gbuf ready; also: all hlds MFMA reads of h(t) complete

    // cell update: thread owns (cb, u0+cu .. +3)
    f32x4 G0 = *(const f32x4*)&gbuf[0][cb][cu];
    f32x4 G1 = *(const f32x4*)&gbuf[1][cb][cu];
    f32x4 G2 = *(const f32x4*)&gbuf[2][cb][cu];
    f32x4 G3 = *(const f32x4*)&gbuf[3][cb][cu];
    const unsigned Tb = ((unsigned)(t + 1) >> 1) & 1u;
    unsigned short hs4[4];
#pragma unroll
    for (int q = 0; q < 4; q++) {
      float gi = sigm(G0[q]), gf = sigm(G1[q]), gg = tanhf(G2[q]), go = sigm(G3[q]);
      cst[q] = gf * cst[q] + gi * gg;
      hs4[q] = (unsigned short)((f2bf(go * tanhf(cst[q])) & 0xFFFEu) | Tb);  // tag in LSB
    }
    const u64 packed =
        (u64)((unsigned)hs4[0] | ((unsigned)hs4[1] << 16)) |
        ((u64)((unsigned)hs4[2] | ((unsigned)hs4[3] << 16)) << 32);

    // fire-and-forget coherent exchange store (tag travels inside the data)
    const int slw = (t + 1) & 1;
    astore64(hbT + slw * 4096 + (cb * 128 + ((u0 + cu) >> 2)), packed);
    // own slice -> LDS directly (local, no round-trip)
    *(u64*)&hlds[cb][u0 + cu] = packed;

    // off critical path: Hout store + next-step xW prefetch
    *(uint2*)(Hout + ((size_t)time * BB + cb) * 1024 + dir * HH + u0 + cu) =
        make_uint2((unsigned)packed, (unsigned)(packed >> 32));
    {
      const int tn = (t + 1 < SS) ? (t + 1) : t;
      const int timen = dir ? (SS - 1 - tn) : tn;
#pragma unroll
      for (int j = 0; j < 2; j++)
#pragma unroll
        for (int i = 0; i < 2; i++)
          xv[i][j] = *(const f32x4*)(xW + ((size_t)timen * GG + wave * HH + u0 + j * 16 + l15) * BB +
                                     i * 16 + quad * 4);
    }

    // stage h(t+1) for the other 15 slices; validity = LSB tag match
    if (t + 1 < SS && !ownCol) {
      const u64 tmask = 0x0001000100010001ULL;
      const u64 tpat = Tb ? tmask : 0ULL;
      const u64* src = hbT + slw * 4096;
      u64 v[16];
#pragma unroll
      for (int i = 0; i < 16; i++) v[i] = aload64(src + (bb0 + 2 * i) * 128 + guc);
      for (;;) {
        unsigned st = 0;
#pragma unroll
        for (int i = 0; i < 16; i++)
          if (((v[i] ^ tpat) & tmask) != 0ULL) st |= 1u << i;
        if (!__any(st)) break;
#pragma unroll
        for (int i = 0; i < 16; i++)
          if (st & (1u << i)) v[i] = aload64(src + (bb0 + 2 * i) * 128 + guc);
      }
#pragma unroll
      for (int i = 0; i < 16; i++) *(u64*)&hlds[bb0 + 2 * i][guc * 4] = v[i];
    }
    __syncthreads();
  }
}

// ---------------- final linear: out[b][s][c] = H1[s*32+b][:] . Wout[c][:] + bout[c]
__global__ __launch_bounds__(256) void k_out(const unsigned short* __restrict__ H1,
                                             const float* __restrict__ Wout,
                                             const float* __restrict__ bout,
                                             float* __restrict__ out) {
  __shared__ float rows[8][1024];
  __shared__ float ps[8][32][8];  // [kpart][class][row]
  const int rb = blockIdx.x * 8;
  const int tid = threadIdx.x;
  for (int idx = tid; idx < 8 * 1024; idx += 256) {
    int r = idx >> 10, k = idx & 1023;
    rows[r][k] = bf2f(H1[(size_t)(rb + r) * 1024 + k]);
  }
  __syncthreads();
  const int c = tid & 31, p = tid >> 5;
  float acc[8] = {0.f, 0.f, 0.f, 0.f, 0.f, 0.f, 0.f, 0.f};
  if (c < NCLS) {
    const float* wr = Wout + (size_t)c * 1024 + p * 128;
    for (int k = 0; k < 128; k++) {
      float w = wr[k];
#pragma unroll
      for (int r = 0; r < 8; r++) acc[r] += rows[r][p * 128 + k] * w;
    }
  }
#pragma unroll
  for (int r = 0; r < 8; r++) ps[p][c][r] = acc[r];
  __syncthreads();
  if (p == 0 && c < NCLS) {
    for (int r = 0; r < 8; r++) {
      float v = bout[c];
#pragma unroll
      for (int q = 0; q < 8; q++) v += ps[q][c][r];
      int row = rb + r, s = row >> 5, b = row & 31;
      out[((size_t)b * SS + s) * NCLS + c] = v;
    }
  }
}

// ---------------------------------------------------------------------------
extern "C" void kernel_launch(void* const* d_in, const int* in_sizes, int n_in,
                              void* d_out, int out_size, void* d_ws, size_t ws_size,
                              hipStream_t stream) {
  const float* hs     = (const float*)d_in[0];
  const int*   roles  = (const int*)d_in[1];
  const int*   preds  = (const int*)d_in[2];
  const float* Wih0f  = (const float*)d_in[3];
  const float* Whh0f  = (const float*)d_in[4];
  const float* bih0f  = (const float*)d_in[5];
  const float* bhh0f  = (const float*)d_in[6];
  const float* Wih0b  = (const float*)d_in[7];
  const float* Whh0b  = (const float*)d_in[8];
  const float* bih0b  = (const float*)d_in[9];
  const float* bhh0b  = (const float*)d_in[10];
  const float* Wih1f  = (const float*)d_in[11];
  const float* Whh1f  = (const float*)d_in[12];
  const float* bih1f  = (const float*)d_in[13];
  const float* bhh1f  = (const float*)d_in[14];
  const float* Wih1b  = (const float*)d_in[15];
  const float* Whh1b  = (const float*)d_in[16];
  const float* bih1b  = (const float*)d_in[17];
  const float* bhh1b  = (const float*)d_in[18];
  const float* Wout   = (const float*)d_in[19];
  const float* bout   = (const float*)d_in[20];
  (void)in_sizes; (void)n_in; (void)out_size; (void)ws_size;

  char* ws = (char*)d_ws;
  size_t off = 0;
  auto alloc = [&](size_t bytes) -> char* {
    char* p = ws + off;
    off += (bytes + 255) & ~(size_t)255;
    return p;
  };
  float* xWf = (float*)alloc((size_t)SS * GG * BB * 4);       // 67.1 MB (reused L0/L1)
  float* xWb = (float*)alloc((size_t)SS * GG * BB * 4);       // 67.1 MB
  unsigned short* A0  = (unsigned short*)alloc((size_t)8192 * 800 * 2);
  unsigned short* H0p = (unsigned short*)alloc((size_t)8192 * 1024 * 2);
  unsigned short* H1p = (unsigned short*)alloc((size_t)8192 * 1024 * 2);
  unsigned short* Wb0f = (unsigned short*)alloc((size_t)GG * 800 * 2);
  unsigned short* Wb0b = (unsigned short*)alloc((size_t)GG * 800 * 2);
  unsigned short* Wb1f = (unsigned short*)alloc((size_t)GG * 1024 * 2);
  unsigned short* Wb1b = (unsigned short*)alloc((size_t)GG * 1024 * 2);
  unsigned short* Wh0f = (unsigned short*)alloc((size_t)GG * HH * 2);
  unsigned short* Wh0b = (unsigned short*)alloc((size_t)GG * HH * 2);
  unsigned short* Wh1f = (unsigned short*)alloc((size_t)GG * HH * 2);
  unsigned short* Wh1b = (unsigned short*)alloc((size_t)GG * HH * 2);
  float* bsum = (float*)alloc(4 * GG * 4);
  float* mw   = (float*)alloc((size_t)BB * SS * 4);
  int*   idxp = (int*)alloc(256);
  // h exchange: [dir][slot][4096] u64 = 128KB per layer; tag-validated
  u64* hbuf0 = (u64*)alloc(131072);
  u64* hbuf1 = (u64*)alloc(131072);

  k_hinit<<<64, 256, 0, stream>>>(hbuf0, hbuf1);

  k_convpad<<<1024, 256, 0, stream>>>(Wih0f, Wb0f, GG, 770, 800);
  k_convpad<<<1024, 256, 0, stream>>>(Wih0b, Wb0b, GG, 770, 800);
  k_convpad<<<1024, 256, 0, stream>>>(Wih1f, Wb1f, GG, 1024, 1024);
  k_convpad<<<1024, 256, 0, stream>>>(Wih1b, Wb1b, GG, 1024, 1024);
  k_convpad<<<1024, 256, 0, stream>>>(Whh0f, Wh0f, GG, 512, 512);
  k_convpad<<<1024, 256, 0, stream>>>(Whh0b, Wh0b, GG, 512, 512);
  k_convpad<<<1024, 256, 0, stream>>>(Whh1f, Wh1f, GG, 512, 512);
  k_convpad<<<1024, 256, 0, stream>>>(Whh1b, Wh1b, GG, 512, 512);
  k_biassum<<<8, 256, 0, stream>>>(bih0f, bhh0f, bsum);
  k_biassum<<<8, 256, 0, stream>>>(bih0b, bhh0b, bsum + 2048);
  k_biassum<<<8, 256, 0, stream>>>(bih1f, bhh1f, bsum + 4096);
  k_biassum<<<8, 256, 0, stream>>>(bih1b, bhh1b, bsum + 6144);

  k_buildA0<<<BB * SS, 256, 0, stream>>>(hs, roles, mw, A0);
  k_idxpred<<<BB, 64, 0, stream>>>(preds, idxp);
  k_predfeat<<<32, 256, 0, stream>>>(mw, idxp, A0);

  dim3 gg(16, 64);
  k_gemm_bt<<<gg, 256, 0, stream>>>(A0, Wb0f, bsum, xWf, 800);
  k_gemm_bt<<<gg, 256, 0, stream>>>(A0, Wb0b, bsum + 2048, xWb, 800);
  k_recurrent<<<2 * NWG, 256, 0, stream>>>(xWf, xWb, Wh0f, Wh0b, hbuf0, H0p);
  k_gemm_bt<<<gg, 256, 0, stream>>>(H0p, Wb1f, bsum + 4096, xWf, 1024);
  k_gemm_bt<<<gg, 256, 0, stream>>>(H0p, Wb1b, bsum + 6144, xWb, 1024);
  k_recurrent<<<2 * NWG, 256, 0, stream>>>(xWf, xWb, Wh1f, Wh1b, hbuf1, H1p);
  k_out<<<1024, 256, 0, stream>>>(H1p, Wout, bout, (float*)d_out);
}

// Round 7
// 2672.459 us; speedup vs baseline: 1.0503x; 1.0503x over previous
//
#include <hip/hip_runtime.h>
#include <hip/hip_bf16.h>
#include <math.h>

#define BB 32
#define SS 256
#define EE 768
#define HH 512
#define GG 2048   // 4*H
#define NCLS 30
#define NWG 16    // workgroups per LSTM direction

typedef __attribute__((ext_vector_type(8))) short bf16x8;
typedef __attribute__((ext_vector_type(4))) float f32x4;
typedef unsigned long long u64;

__device__ inline unsigned short f2bf(float f) {
  union { float f; unsigned int u; } v; v.f = f;
  unsigned int r = v.u + 0x7fffu + ((v.u >> 16) & 1u);
  return (unsigned short)(r >> 16);
}
__device__ inline float bf2f(unsigned short u) {
  union { unsigned int u; float f; } v; v.u = ((unsigned int)u) << 16;
  return v.f;
}
__device__ inline float sigm(float x) { return 1.f / (1.f + expf(-x)); }

__device__ inline void load_lds16(const void* g, void* l) {
  __builtin_amdgcn_global_load_lds(
      (const __attribute__((address_space(1))) void*)g,
      (__attribute__((address_space(3))) void*)l, 16, 0, 0);
}
// agent-coherent DMA variant: aux=17 = SC0|SC1 (L1+L2 bypass, reads MALL)
__device__ inline void load_lds16c(const void* g, void* l) {
  __builtin_amdgcn_global_load_lds(
      (const __attribute__((address_space(1))) void*)g,
      (__attribute__((address_space(3))) void*)l, 16, 0, 17);
}

// agent-scope coherent ops (visible at the MALL; 8B aligned = single-copy atomic)
__device__ inline u64 aload64(const u64* p) {
  return __hip_atomic_load(p, __ATOMIC_RELAXED, __HIP_MEMORY_SCOPE_AGENT);
}
__device__ inline void astore64(u64* p, u64 v) {
  __hip_atomic_store(p, v, __ATOMIC_RELAXED, __HIP_MEMORY_SCOPE_AGENT);
}
__device__ inline void wait_vm0() {
  asm volatile("s_waitcnt vmcnt(0)" ::: "memory");
}

// ---------------- weight conversion (fp32 -> bf16, with K padding) ----------
__global__ void k_convpad(const float* __restrict__ src, unsigned short* __restrict__ dst,
                          int R, int Ks, int Kd) {
  int n = R * Kd;
  for (int i = blockIdx.x * blockDim.x + threadIdx.x; i < n; i += gridDim.x * blockDim.x) {
    int r = i / Kd, k = i - r * Kd;
    dst[i] = (k < Ks) ? f2bf(src[(size_t)r * Ks + k]) : (unsigned short)0;
  }
}

__global__ void k_biassum(const float* __restrict__ a, const float* __restrict__ b,
                          float* __restrict__ o) {
  int i = blockIdx.x * 256 + threadIdx.x;
  if (i < GG) o[i] = a[i] + b[i];
}

// ---------------- h-exchange buffer init: slot0 LSB=0, slot1 LSB=1 ---------
__global__ void k_hinit(u64* __restrict__ h0, u64* __restrict__ h1) {
  int i = blockIdx.x * 256 + threadIdx.x;  // [dir][slot][4096] = 16384 per layer
  if (i < 16384) {
    u64 v = ((i >> 12) & 1) ? 0x0001000100010001ULL : 0ULL;
    h0[i] = v;
    h1[i] = v;
  }
}

// ---------------- idx_pred[b] = argmax (first max) of predicates -----------
__global__ void k_idxpred(const int* __restrict__ pred, int* __restrict__ idxp) {
  int b = blockIdx.x, l = threadIdx.x;  // 64 threads
  const int* pb = pred + b * SS;
  int4 v = *(const int4*)(pb + l * 4);
  int loc = 0x7fffffff;
  if (v.w == 1) loc = 4 * l + 3;
  if (v.z == 1) loc = 4 * l + 2;
  if (v.y == 1) loc = 4 * l + 1;
  if (v.x == 1) loc = 4 * l + 0;
  for (int off = 32; off > 0; off >>= 1) {
    int o = __shfl_down(loc, off);
    loc = min(loc, o);
  }
  if (l == 0) idxp[b] = (loc == 0x7fffffff) ? 0 : loc;
}

// ---------------- A0 build + fused mean_word (single pass over hs) ---------
__global__ void k_buildA0(const float* __restrict__ hs, const int* __restrict__ roles,
                          float* __restrict__ mw, unsigned short* __restrict__ A0) {
  int blk = blockIdx.x;           // s*32 + b
  int s = blk >> 5, b = blk & 31;
  unsigned short* row = A0 + (size_t)blk * 800;
  size_t base = ((size_t)b * SS + s) * EE;
  const size_t LSTR = (size_t)BB * SS * EE;
  __shared__ float red[256];
  float part = 0.f;
  for (int k = threadIdx.x; k < EE; k += 256) {
    float v = (hs[base + k] + hs[base + LSTR + k] + hs[base + 2 * LSTR + k] +
               hs[base + 3 * LSTR + k]) * 0.25f;
    part += v;
    row[k] = f2bf(v);
  }
  red[threadIdx.x] = part;
  __syncthreads();
  for (int s2 = 128; s2 > 0; s2 >>= 1) {
    if (threadIdx.x < s2) red[threadIdx.x] += red[threadIdx.x + s2];
    __syncthreads();
  }
  if (threadIdx.x == 0) mw[b * SS + s] = red[0] * (1.f / 768.f);
  if (threadIdx.x == 1) {
    int rl = roles[b * SS + s];
    row[769] = f2bf((rl != 0 && rl != -100) ? 1.f : 0.f);
  }
  if (threadIdx.x < 30) row[770 + threadIdx.x] = 0;
}

// fill the predicate-relative delta feature (col 768) after idxp is known
__global__ void k_predfeat(const float* __restrict__ mw, const int* __restrict__ idxp,
                           unsigned short* __restrict__ A0) {
  int i = blockIdx.x * 256 + threadIdx.x;  // b*256 + s
  int b = i >> 8, s = i & 255;
  float d = mw[i] - mw[b * SS + idxp[b]];
  A0[(size_t)(s * 32 + b) * 800 + 768] = f2bf(d);
}

// ---------------- GEMM-BT: C[s][n][b] = A[s*32+b][:] . W[n][:] + bias[n] ---
__global__ __launch_bounds__(256) void k_gemm_bt(const unsigned short* __restrict__ A,
                                                 const unsigned short* __restrict__ W,
                                                 const float* __restrict__ bias,
                                                 float* __restrict__ C, int K) {
  __shared__ unsigned short As[128 * 32];
  __shared__ unsigned short Bs[128 * 32];
  const int tid = threadIdx.x;
  const int wave = tid >> 6, lane = tid & 63;
  const int l15 = lane & 15, quad = lane >> 4;
  const int m0 = blockIdx.y * 128, n0 = blockIdx.x * 128;
  const int wr = (wave >> 1) * 64, wc = (wave & 1) * 64;
  const int srow = wave * 16 + (lane >> 2);
  const int scol = (lane & 3) * 8;

  f32x4 acc[4][4];
#pragma unroll
  for (int i = 0; i < 4; i++)
#pragma unroll
    for (int j = 0; j < 4; j++) acc[i][j] = (f32x4){0.f, 0.f, 0.f, 0.f};

  for (int k0 = 0; k0 < K; k0 += 32) {
#pragma unroll
    for (int rep = 0; rep < 2; rep++) {
      load_lds16(A + (size_t)(m0 + rep * 64 + srow) * K + k0 + scol,
                 &As[(rep * 64 + wave * 16) * 32]);
      load_lds16(W + (size_t)(n0 + rep * 64 + srow) * K + k0 + scol,
                 &Bs[(rep * 64 + wave * 16) * 32]);
    }
    __syncthreads();
    bf16x8 af[4], bfr[4];
#pragma unroll
    for (int i = 0; i < 4; i++) af[i] = *(const bf16x8*)&As[(wr + i * 16 + l15) * 32 + quad * 8];
#pragma unroll
    for (int j = 0; j < 4; j++) bfr[j] = *(const bf16x8*)&Bs[(wc + j * 16 + l15) * 32 + quad * 8];
#pragma unroll
    for (int i = 0; i < 4; i++)
#pragma unroll
      for (int j = 0; j < 4; j++)
        acc[i][j] = __builtin_amdgcn_mfma_f32_16x16x32_bf16(af[i], bfr[j], acc[i][j], 0, 0, 0);
    __syncthreads();
  }

#pragma unroll
  for (int j = 0; j < 4; j++) {
    int n = n0 + wc + j * 16 + l15;
    float bv = bias[n];
#pragma unroll
    for (int i = 0; i < 4; i++) {
      int m = m0 + wr + i * 16 + quad * 4;  // row = s*32+b, 4 consecutive b
      int s = m >> 5, b = m & 31;
      f32x4 v = acc[i][j];
      f32x4 outv = {v[0] + bv, v[1] + bv, v[2] + bv, v[3] + bv};
      *(f32x4*)(C + ((size_t)s * GG + n) * BB + b) = outv;
    }
  }
}

// ---------------- persistent BiLSTM recurrence (one layer) ------------------
// 32 WGs: dir = wg>>4, slice = wg&15 -> hidden units [32*slice, +32)
// wave w = gate type w (i,f,g,o), rows w*512 + u0 + [0,32)
// R6 tag-in-LSB scheme kept. R7 changes:
//  (1) staging via global_load_lds DMA (aux=17 sc0|sc1): 8 instrs/wave for 8KB,
//      tag-check in LDS, bounded row-retry + proven aload64 cleanup.
//      (R5/R6 invariance showed the 16 per-thread coherent VGPR loads were the
//      ~4us/step floor -- near-serialized on the L2-bypass path.)
//  (2) bfrag pinned via volatile inline-asm loads (R3-R6: compiler kept
//      rematerializing Whh loads in-loop; VGPR_Count<128 proved non-residency).
__global__ __launch_bounds__(256, 1) void k_recurrent(const float* __restrict__ xWf,
                                                      const float* __restrict__ xWb,
                                                      const unsigned short* __restrict__ WhhF,
                                                      const unsigned short* __restrict__ WhhB,
                                                      u64* __restrict__ hbuf,
                                                      unsigned short* __restrict__ Hout) {
  const int wg = blockIdx.x, dir = wg >> 4, slice = wg & 15;
  const int tid = threadIdx.x, wave = tid >> 6, lane = tid & 63;
  const int l15 = lane & 15, quad = lane >> 4;
  const int u0 = slice * 32;
  const unsigned short* Whh = dir ? WhhB : WhhF;
  const float* xW = dir ? xWb : xWf;
  u64* hbT = hbuf + (size_t)dir * 8192;     // 2 slots x 4096 granules (8B = 4 units)

  // h staging in LDS: [batch 32][528 shorts] (row = 1KB data + 32B pad)
  __shared__ __attribute__((aligned(16))) short hlds[32][528];
  __shared__ float gbuf[4][32][32];  // [gate][batch][unit_local]

  // zero h(t=0)
  for (int i = tid; i < 32 * 264; i += 256) ((unsigned int*)hlds)[i] = 0;

  // Whh B-fragments: volatile asm loads -> cannot be rematerialized -> resident
  bf16x8 bfrag[2][16];
#pragma unroll
  for (int j = 0; j < 2; j++) {
    const unsigned short* wrow = Whh + (size_t)(wave * HH + u0 + j * 16 + l15) * HH + quad * 8;
#pragma unroll
    for (int kk = 0; kk < 16; kk++)
      asm volatile("global_load_dwordx4 %0, %1, off"
                   : "=v"(bfrag[j][kk]) : "v"(wrow + kk * 32));
  }
  wait_vm0();

  const int cb = tid >> 3;           // batch this thread updates (32)
  const int cu = (tid & 7) * 4;      // 4 consecutive local units
  float cst[4] = {0.f, 0.f, 0.f, 0.f};
  const int wrow = wave * 8;         // this wave stages LDS rows [wrow, wrow+8)

  // prefetch xW for t=0
  f32x4 xv[2][2];
  {
    const int time0 = dir ? (SS - 1) : 0;
#pragma unroll
    for (int j = 0; j < 2; j++)
#pragma unroll
      for (int i = 0; i < 2; i++)
        xv[i][j] = *(const f32x4*)(xW + ((size_t)time0 * GG + wave * HH + u0 + j * 16 + l15) * BB +
                                   i * 16 + quad * 4);
  }
  __syncthreads();

  for (int t = 0; t < SS; t++) {
    const int time = dir ? (SS - 1 - t) : t;

    f32x4 acc[2][2];
#pragma unroll
    for (int i = 0; i < 2; i++)
#pragma unroll
      for (int j = 0; j < 2; j++) acc[i][j] = xv[i][j];

#pragma unroll
    for (int kk = 0; kk < 16; kk++) {
      bf16x8 a0 = *(const bf16x8*)&hlds[l15][quad * 8 + kk * 32];
      bf16x8 a1 = *(const bf16x8*)&hlds[16 + l15][quad * 8 + kk * 32];
      acc[0][0] = __builtin_amdgcn_mfma_f32_16x16x32_bf16(a0, bfrag[0][kk], acc[0][0], 0, 0, 0);
      acc[0][1] = __builtin_amdgcn_mfma_f32_16x16x32_bf16(a0, bfrag[1][kk], acc[0][1], 0, 0, 0);
      acc[1][0] = __builtin_amdgcn_mfma_f32_16x16x32_bf16(a1, bfrag[0][kk], acc[1][0], 0, 0, 0);
      acc[1][1] = __builtin_amdgcn_mfma_f32_16x16x32_bf16(a1, bfrag[1][kk], acc[1][1], 0, 0, 0);
    }
#pragma unroll
    for (int i = 0; i < 2; i++)
#pragma unroll
      for (int j = 0; j < 2; j++)
#pragma unroll
        for (int r = 0; r < 4; r++)
          gbuf[wave][i * 16 + quad * 4 + r][j * 16 + l15] = acc[i][j][r];
    __syncthreads();   // gbuf ready; also: all hlds MFMA reads of h(t) complete

    // cell update: thread owns (cb, u0+cu .. +3)
    f32x4 G0 = *(const f32x4*)&gbuf[0][cb][cu];
    f32x4 G1 = *(const f32x4*)&gbuf[1][cb][cu];
    f32x4 G2 = *(const f32x4*)&gbuf[2][cb][cu];
    f32x4 G3 = *(const f32x4*)&gbuf[3][cb][cu];
    const unsigned Tb = ((unsigned)(t + 1) >> 1) & 1u;
    unsigned short hs4[4];
#pragma unroll
    for (int q = 0; q < 4; q++) {
      float gi = sigm(G0[q]), gf = sigm(G1[q]), gg = tanhf(G2[q]), go = sigm(G3[q]);
      cst[q] = gf * cst[q] + gi * gg;
      hs4[q] = (unsigned short)((f2bf(go * tanhf(cst[q])) & 0xFFFEu) | Tb);  // tag in LSB
    }
    const u64 packed =
        (u64)((unsigned)hs4[0] | ((unsigned)hs4[1] << 16)) |
        ((u64)((unsigned)hs4[2] | ((unsigned)hs4[3] << 16)) << 32);

    // fire-and-forget coherent exchange store (tag travels inside the data)
    const int slw = (t + 1) & 1;
    astore64(hbT + slw * 4096 + (cb * 128 + ((u0 + cu) >> 2)), packed);

    // off critical path: Hout store + next-step xW prefetch
    *(uint2*)(Hout + ((size_t)time * BB + cb) * 1024 + dir * HH + u0 + cu) =
        make_uint2((unsigned)packed, (unsigned)(packed >> 32));
    {
      const int tn = (t + 1 < SS) ? (t + 1) : t;
      const int timen = dir ? (SS - 1 - tn) : tn;
#pragma unroll
      for (int j = 0; j < 2; j++)
#pragma unroll
        for (int i = 0; i < 2; i++)
          xv[i][j] = *(const f32x4*)(xW + ((size_t)timen * GG + wave * HH + u0 + j * 16 + l15) * BB +
                                     i * 16 + quad * 4);
    }

    // stage h(t+1): per-wave DMA of 8 LDS rows, tag-validated, bounded retry
    if (t + 1 < SS) {
      const u64 tmask = 0x0001000100010001ULL;
      const u64 tpat = Tb ? tmask : 0ULL;
      const char* srcB = (const char*)(hbT + slw * 4096);
#pragma unroll
      for (int r = 0; r < 8; r++)
        load_lds16c(srcB + ((wrow + r) << 10) + (lane << 4), &hlds[wrow + r][0]);
      unsigned stale = 0xFFFFu;  // bits 2r,2r+1 = this lane's two granules of row r
      for (int round = 0; round < 5; round++) {
        wait_vm0();
        stale = 0;
#pragma unroll
        for (int r = 0; r < 8; r++) {
          u64 v0 = *(const u64*)&hlds[wrow + r][8 * lane];
          u64 v1 = *(const u64*)&hlds[wrow + r][8 * lane + 4];
          if (((v0 ^ tpat) & tmask) != 0ULL) stale |= 1u << (2 * r);
          if (((v1 ^ tpat) & tmask) != 0ULL) stale |= 1u << (2 * r + 1);
        }
        if (!__any(stale != 0)) break;
        if (round == 4) break;
#pragma unroll
        for (int r = 0; r < 8; r++) {
          if (__any((stale >> (2 * r)) & 3))
            load_lds16c(srcB + ((wrow + r) << 10) + (lane << 4), &hlds[wrow + r][0]);
        }
      }
      if (__any(stale != 0)) {
        // proven-path cleanup: per-granule agent atomic loads until valid
        const u64* src = hbT + slw * 4096;
#pragma unroll
        for (int r = 0; r < 8; r++) {
#pragma unroll
          for (int c = 0; c < 2; c++) {
            if ((stale >> (2 * r + c)) & 1) {
              const int g = (wrow + r) * 128 + 2 * lane + c;
              u64 x = aload64(src + g);
              while (((x ^ tpat) & tmask) != 0ULL) x = aload64(src + g);
              *(u64*)&hlds[wrow + r][8 * lane + 4 * c] = x;
            }
          }
        }
      }
    }
    __syncthreads();
  }
}

// ---------------- final linear: out[b][s][c] = H1[s*32+b][:] . Wout[c][:] + bout[c]
__global__ __launch_bounds__(256) void k_out(const unsigned short* __restrict__ H1,
                                             const float* __restrict__ Wout,
                                             const float* __restrict__ bout,
                                             float* __restrict__ out) {
  __shared__ float rows[8][1024];
  __shared__ float ps[8][32][8];  // [kpart][class][row]
  const int rb = blockIdx.x * 8;
  const int tid = threadIdx.x;
  for (int idx = tid; idx < 8 * 1024; idx += 256) {
    int r = idx >> 10, k = idx & 1023;
    rows[r][k] = bf2f(H1[(size_t)(rb + r) * 1024 + k]);
  }
  __syncthreads();
  const int c = tid & 31, p = tid >> 5;
  float acc[8] = {0.f, 0.f, 0.f, 0.f, 0.f, 0.f, 0.f, 0.f};
  if (c < NCLS) {
    const float* wr = Wout + (size_t)c * 1024 + p * 128;
    for (int k = 0; k < 128; k++) {
      float w = wr[k];
#pragma unroll
      for (int r = 0; r < 8; r++) acc[r] += rows[r][p * 128 + k] * w;
    }
  }
#pragma unroll
  for (int r = 0; r < 8; r++) ps[p][c][r] = acc[r];
  __syncthreads();
  if (p == 0 && c < NCLS) {
    for (int r = 0; r < 8; r++) {
      float v = bout[c];
#pragma unroll
      for (int q = 0; q < 8; q++) v += ps[q][c][r];
      int row = rb + r, s = row >> 5, b = row & 31;
      out[((size_t)b * SS + s) * NCLS + c] = v;
    }
  }
}

// ---------------------------------------------------------------------------
extern "C" void kernel_launch(void* const* d_in, const int* in_sizes, int n_in,
                              void* d_out, int out_size, void* d_ws, size_t ws_size,
                              hipStream_t stream) {
  const float* hs     = (const float*)d_in[0];
  const int*   roles  = (const int*)d_in[1];
  const int*   preds  = (const int*)d_in[2];
  const float* Wih0f  = (const float*)d_in[3];
  const float* Whh0f  = (const float*)d_in[4];
  const float* bih0f  = (const float*)d_in[5];
  const float* bhh0f  = (const float*)d_in[6];
  const float* Wih0b  = (const float*)d_in[7];
  const float* Whh0b  = (const float*)d_in[8];
  const float* bih0b  = (const float*)d_in[9];
  const float* bhh0b  = (const float*)d_in[10];
  const float* Wih1f  = (const float*)d_in[11];
  const float* Whh1f  = (const float*)d_in[12];
  const float* bih1f  = (const float*)d_in[13];
  const float* bhh1f  = (const float*)d_in[14];
  const float* Wih1b  = (const float*)d_in[15];
  const float* Whh1b  = (const float*)d_in[16];
  const float* bih1b  = (const float*)d_in[17];
  const float* bhh1b  = (const float*)d_in[18];
  const float* Wout   = (const float*)d_in[19];
  const float* bout   = (const float*)d_in[20];
  (void)in_sizes; (void)n_in; (void)out_size; (void)ws_size;

  char* ws = (char*)d_ws;
  size_t off = 0;
  auto alloc = [&](size_t bytes) -> char* {
    char* p = ws + off;
    off += (bytes + 255) & ~(size_t)255;
    return p;
  };
  float* xWf = (float*)alloc((size_t)SS * GG * BB * 4);       // 67.1 MB (reused L0/L1)
  float* xWb = (float*)alloc((size_t)SS * GG * BB * 4);       // 67.1 MB
  unsigned short* A0  = (unsigned short*)alloc((size_t)8192 * 800 * 2);
  unsigned short* H0p = (unsigned short*)alloc((size_t)8192 * 1024 * 2);
  unsigned short* H1p = (unsigned short*)alloc((size_t)8192 * 1024 * 2);
  unsigned short* Wb0f = (unsigned short*)alloc((size_t)GG * 800 * 2);
  unsigned short* Wb0b = (unsigned short*)alloc((size_t)GG * 800 * 2);
  unsigned short* Wb1f = (unsigned short*)alloc((size_t)GG * 1024 * 2);
  unsigned short* Wb1b = (unsigned short*)alloc((size_t)GG * 1024 * 2);
  unsigned short* Wh0f = (unsigned short*)alloc((size_t)GG * HH * 2);
  unsigned short* Wh0b = (unsigned short*)alloc((size_t)GG * HH * 2);
  unsigned short* Wh1f = (unsigned short*)alloc((size_t)GG * HH * 2);
  unsigned short* Wh1b = (unsigned short*)alloc((size_t)GG * HH * 2);
  float* bsum = (float*)alloc(4 * GG * 4);
  float* mw   = (float*)alloc((size_t)BB * SS * 4);
  int*   idxp = (int*)alloc(256);
  // h exchange: [dir][slot][4096] u64 = 128KB per layer; tag-validated
  u64* hbuf0 = (u64*)alloc(131072);
  u64* hbuf1 = (u64*)alloc(131072);

  k_hinit<<<64, 256, 0, stream>>>(hbuf0, hbuf1);

  k_convpad<<<1024, 256, 0, stream>>>(Wih0f, Wb0f, GG, 770, 800);
  k_convpad<<<1024, 256, 0, stream>>>(Wih0b, Wb0b, GG, 770, 800);
  k_convpad<<<1024, 256, 0, stream>>>(Wih1f, Wb1f, GG, 1024, 1024);
  k_convpad<<<1024, 256, 0, stream>>>(Wih1b, Wb1b, GG, 1024, 1024);
  k_convpad<<<1024, 256, 0, stream>>>(Whh0f, Wh0f, GG, 512, 512);
  k_convpad<<<1024, 256, 0, stream>>>(Whh0b, Wh0b, GG, 512, 512);
  k_convpad<<<1024, 256, 0, stream>>>(Whh1f, Wh1f, GG, 512, 512);
  k_convpad<<<1024, 256, 0, stream>>>(Whh1b, Wh1b, GG, 512, 512);
  k_biassum<<<8, 256, 0, stream>>>(bih0f, bhh0f, bsum);
  k_biassum<<<8, 256, 0, stream>>>(bih0b, bhh0b, bsum + 2048);
  k_biassum<<<8, 256, 0, stream>>>(bih1f, bhh1f, bsum + 4096);
  k_biassum<<<8, 256, 0, stream>>>(bih1b, bhh1b, bsum + 6144);

  k_buildA0<<<BB * SS, 256, 0, stream>>>(hs, roles, mw, A0);
  k_idxpred<<<BB, 64, 0, stream>>>(preds, idxp);
  k_predfeat<<<32, 256, 0, stream>>>(mw, idxp, A0);

  dim3 gg(16, 64);
  k_gemm_bt<<<gg, 256, 0, stream>>>(A0, Wb0f, bsum, xWf, 800);
  k_gemm_bt<<<gg, 256, 0, stream>>>(A0, Wb0b, bsum + 2048, xWb, 800);
  k_recurrent<<<2 * NWG, 256, 0, stream>>>(xWf, xWb, Wh0f, Wh0b, hbuf0, H0p);
  k_gemm_bt<<<gg, 256, 0, stream>>>(H0p, Wb1f, bsum + 4096, xWf, 1024);
  k_gemm_bt<<<gg, 256, 0, stream>>>(H0p, Wb1b, bsum + 6144, xWb, 1024);
  k_recurrent<<<2 * NWG, 256, 0, stream>>>(xWf, xWb, Wh1f, Wh1b, hbuf1, H1p);
  k_out<<<1024, 256, 0, stream>>>(H1p, Wout, bout, (float*)d_out);
}